// Round 9
// baseline (144.657 us; speedup 1.0000x reference)
//
#include <hip/hip_runtime.h>

// BasisFunction2D, round 9: kill the HBM scatter (measured: bf2d staged P in
// 128B chunks @ 256KB stride -> 875 GB/s, FETCH 38 MB -> ~43 us fetch-bound).
// Kernel 1 (precompute): grid coords/weights; zc transposed [b][j]; zero out.
// Kernel 2 (repack): read P fully coalesced (each wg streams a contiguous
//   piece of one cell), pack bf16 o-pairs, write Q so each main block's
//   37 KB slice is CONTIGUOUS: Q[(op*32+i)*9248 + cell*32 + j].
//   76 MB sequential read + 38 MB write; Q stays L2/L3-resident in-launch.
// Kernel 3 (main): stage slice by streaming uint4 from Q (sequential, cache
//   hit) into padded LDS; gather identical to R8 (2x ds_read2_b32 per (b,j)
//   serving both outputs, scalar bf16 lerp, f32 acc, atomicAdd over i).

#define NG        16
#define NB        17             // NG+1
#define IN_X      32
#define IN_Z      32
#define OUT_DIM   64
#define BATCH     512
#define CELLS     (NB * NB)      // 289
#define LDS_STR   33             // 32 + 1 pad (element units)
#define XSTR      (NB * LDS_STR) // 561
#define QROW      (CELLS * 32)   // 9248 dwords per block-slice
#define SQT       (QROW / 4)     // 2312 stage quads
#define SNITER    5              // ceil(SQT / 512)

__device__ __forceinline__ void grid_coord(float v,
                                           const float* __restrict__ borders,
                                           const float* __restrict__ inv_len,
                                           int& idx, float& w) {
    float e   = expf(-fabsf(v));
    float cdf = (v > 0.f) ? (1.f - 0.5f * e) : (0.5f * e);
    int t = (int)(cdf * 16.f);
    t = t < 0 ? 0 : (t > NG - 1 ? NG - 1 : t);
    idx = t;
    w = (v - borders[t]) * inv_len[t];
}

// pack two floats as bf16 (round-to-nearest-even), lo = a, hi = b
__device__ __forceinline__ unsigned pack_bf16(float a, float b) {
    unsigned ua = __float_as_uint(a);
    unsigned ub = __float_as_uint(b);
    ua += 0x7FFFu + ((ua >> 16) & 1u);
    ub += 0x7FFFu + ((ub >> 16) & 1u);
    return (ua >> 16) | (ub & 0xFFFF0000u);
}
__device__ __forceinline__ float bf_lo(unsigned u) {
    return __uint_as_float(u << 16);
}
__device__ __forceinline__ float bf_hi(unsigned u) {
    return __uint_as_float(u & 0xFFFF0000u);
}

// 32768 threads: gid<16384 -> x table, else z table (transposed [b][j]).
// Also zeroes out[] (32768 elements).
__global__ void precompute_kernel(const float* __restrict__ x,
                                  const float* __restrict__ z,
                                  const float* __restrict__ borders,
                                  const float* __restrict__ inv_len,
                                  float2* __restrict__ xc,   // [32*512]
                                  uint2* __restrict__ zc2,   // [512][32]
                                  float* __restrict__ out) {
    const int gid = blockIdx.x * blockDim.x + threadIdx.x;
    out[gid] = 0.f;
    int idx; float w;
    if (gid < IN_X * BATCH) {
        grid_coord(x[gid], borders, inv_len, idx, w);
        xc[gid] = make_float2(w, __int_as_float(idx * XSTR));
    } else {
        const int g = gid - IN_X * BATCH;   // g = j*512 + b
        const int j = g >> 9;
        const int b = g & (BATCH - 1);
        grid_coord(z[g], borders, inv_len, idx, w);
        zc2[b * IN_Z + j] = make_uint2(__float_as_uint(w),
                                       (unsigned)(idx * LDS_STR));
    }
}

// grid = 289*4 wgs x 256 threads. wg (cell, quarter q) handles op in
// [q*8, q*8+8). Reads P sequentially (1KB/wave/stream), writes Q rows.
__global__ __launch_bounds__(256)
void repack_kernel(const float* __restrict__ P,
                   unsigned* __restrict__ Q) {
    const int cell = blockIdx.x >> 2;
    const int q    = blockIdx.x & 3;
    const float* Pc = P + (size_t)cell * 65536;   // cell stride 64*32*32

    #pragma unroll
    for (int it = 0; it < 8; ++it) {
        const int t   = threadIdx.x + it * 256;   // 0..2047
        const int opl = t >> 8;                   // 0..7
        const int rem = t & 255;
        const int i   = rem >> 3;                 // 0..31
        const int j4  = (rem & 7) << 2;           // 0,4,..,28
        const int op  = q * 8 + opl;              // o-pair index 0..31

        const float* g = Pc + (size_t)(2 * op) * 1024 + i * 32 + j4;
        const float4 a = *(const float4*)g;            // o = 2*op
        const float4 b = *(const float4*)(g + 1024);   // o = 2*op+1

        unsigned* d = Q + (size_t)(op * 32 + i) * QROW + cell * 32 + j4;
        *(uint4*)d = make_uint4(pack_bf16(a.x, b.x), pack_bf16(a.y, b.y),
                                pack_bf16(a.z, b.z), pack_bf16(a.w, b.w));
    }
}

__global__ __launch_bounds__(512, 8)
void bf2d_kernel(const float2* __restrict__ xc,
                 const uint2* __restrict__ zc2,
                 const unsigned* __restrict__ Q,
                 float* __restrict__ out) {
    // lds[e] = packed bf16 (P[cell,o0,i,j], P[cell,o1,i,j]), e = cell*33 + j
    __shared__ unsigned lds[CELLS * LDS_STR];   // 9537 dwords = 38148 B

    const int tid = threadIdx.x;                // 512 threads = batch element
    const int op  = blockIdx.x & 31;            // o-pair
    const int i   = blockIdx.x >> 5;
    const int o0  = op * 2;

    // ---- stage contiguous Q row into padded LDS ----
    const uint4* Qb = (const uint4*)(Q + (size_t)(op * 32 + i) * QROW);
    #pragma unroll
    for (int t = 0; t < SNITER; ++t) {
        const int k = tid + t * 512;
        if (k < SQT) {
            const int c  = k >> 3;              // cell
            const int j4 = (k & 7) << 2;
            const uint4 v = Qb[k];
            unsigned* d = &lds[c * LDS_STR + j4];
            d[0] = v.x; d[1] = v.y; d[2] = v.z; d[3] = v.w;
        }
    }
    __syncthreads();

    // ---- per-thread: 1 batch element, 2 outputs ----
    const float2 xcv  = xc[i * BATCH + tid];
    const float  wx   = xcv.x;
    const int    xoff = __float_as_int(xcv.y);

    const uint4* zp4 = (const uint4*)(zc2 + (size_t)tid * IN_Z);
    float accx = 0.f, accy = 0.f;
    #pragma unroll 4
    for (int jj = 0; jj < 16; ++jj) {
        const uint4 q = zp4[jj];                 // 2 j's per VMEM load
        {
            const float wz   = __uint_as_float(q.x);
            const int   base = xoff + (int)q.y + 2 * jj;
            const unsigned a0 = lds[base];
            const unsigned a1 = lds[base + LDS_STR];        // ds_read2 pair
            const unsigned b0 = lds[base + XSTR];
            const unsigned b1 = lds[base + XSTR + LDS_STR]; // ds_read2 pair
            const float lox = bf_lo(a0) + wz * (bf_lo(a1) - bf_lo(a0));
            const float loy = bf_hi(a0) + wz * (bf_hi(a1) - bf_hi(a0));
            const float hix = bf_lo(b0) + wz * (bf_lo(b1) - bf_lo(b0));
            const float hiy = bf_hi(b0) + wz * (bf_hi(b1) - bf_hi(b0));
            accx += lox + wx * (hix - lox);
            accy += loy + wx * (hiy - loy);
        }
        {
            const float wz   = __uint_as_float(q.z);
            const int   base = xoff + (int)q.w + 2 * jj + 1;
            const unsigned a0 = lds[base];
            const unsigned a1 = lds[base + LDS_STR];
            const unsigned b0 = lds[base + XSTR];
            const unsigned b1 = lds[base + XSTR + LDS_STR];
            const float lox = bf_lo(a0) + wz * (bf_lo(a1) - bf_lo(a0));
            const float loy = bf_hi(a0) + wz * (bf_hi(a1) - bf_hi(a0));
            const float hix = bf_lo(b0) + wz * (bf_lo(b1) - bf_lo(b0));
            const float hiy = bf_hi(b0) + wz * (bf_hi(b1) - bf_hi(b0));
            accx += lox + wx * (hix - lox);
            accy += loy + wx * (hiy - loy);
        }
    }

    atomicAdd(&out[o0 * BATCH + tid],       accx);
    atomicAdd(&out[(o0 + 1) * BATCH + tid], accy);
}

extern "C" void kernel_launch(void* const* d_in, const int* in_sizes, int n_in,
                              void* d_out, int out_size, void* d_ws, size_t ws_size,
                              hipStream_t stream) {
    const float* x       = (const float*)d_in[0];   // (32, 512)
    const float* z       = (const float*)d_in[1];   // (32, 512)
    const float* P       = (const float*)d_in[2];   // (17,17,64,32,32)
    const float* borders = (const float*)d_in[3];   // (17,)
    const float* inv_len = (const float*)d_in[4];   // (16,)
    float* out = (float*)d_out;                     // (64, 512) = 32768

    float2*   xc  = (float2*)d_ws;                  // 16384 float2 = 128 KB
    uint2*    zc2 = (uint2*)(xc + IN_X * BATCH);    // 16384 uint2  = 128 KB
    unsigned* Q   = (unsigned*)((char*)d_ws + 262144); // 1024*9248 dw = 36.1 MB

    precompute_kernel<<<dim3(128), dim3(256), 0, stream>>>(
        x, z, borders, inv_len, xc, zc2, out);

    repack_kernel<<<dim3(CELLS * 4), dim3(256), 0, stream>>>(P, Q);

    bf2d_kernel<<<dim3((OUT_DIM / 2) * IN_X), dim3(512), 0, stream>>>(
        xc, zc2, Q, out);
}

// Round 10
// 122.231 us; speedup vs baseline: 1.1835x; 1.1835x over previous
//
#include <hip/hip_runtime.h>

// BasisFunction2D, round 10: fix the staging DRAM scatter IN PLACE.
// R8 profile: block=(op,i) stages P in 128-B chunks -> 875 GB/s, fetch-bound.
// Now block = (op, i-quad) -> each block reads two CONTIGUOUS 512-B stripes
// per cell (4x burst length, same total bytes, each P element read once).
// LDS: 289 cells x 4 i x 32 j bf16-o-pair dwords, cell stride 133 (odd ->
// banks ~uniform for random gather; gz-delta 133 dwords fits ds_read2).
// 153.7 KB LDS -> 1 block/CU, 1024 threads = 16 waves/CU, grid = 256.
// Gather: thread = (b, il-pair); one coalesced zc read per j serves both il;
// scalar bf16 lerp (R5 math); f32 acc; 2 atomicAdd/thread (half of R5).

#define NG        16
#define NB        17              // NG+1
#define IN_X      32
#define IN_Z      32
#define OUT_DIM   64
#define BATCH     512
#define CELLS     (NB * NB)       // 289
#define CSTRIDE   133             // 4*33 + 1: odd cell stride (bank spread)
#define ILSTRIDE  33              // per-i row stride inside a cell
#define XSTR_A    (NB * CSTRIDE)  // 2261: gx -> +17 cells
#define STASKS    (CELLS * 32)    // 9248 float4-pair staging tasks

__device__ __forceinline__ void grid_coord(float v,
                                           const float* __restrict__ borders,
                                           const float* __restrict__ inv_len,
                                           int& idx, float& w) {
    float e   = expf(-fabsf(v));
    float cdf = (v > 0.f) ? (1.f - 0.5f * e) : (0.5f * e);
    int t = (int)(cdf * 16.f);
    t = t < 0 ? 0 : (t > NG - 1 ? NG - 1 : t);
    idx = t;
    w = (v - borders[t]) * inv_len[t];
}

// pack two floats as bf16 (round-to-nearest-even), lo = a, hi = b
__device__ __forceinline__ unsigned pack_bf16(float a, float b) {
    unsigned ua = __float_as_uint(a);
    unsigned ub = __float_as_uint(b);
    ua += 0x7FFFu + ((ua >> 16) & 1u);
    ub += 0x7FFFu + ((ub >> 16) & 1u);
    return (ua >> 16) | (ub & 0xFFFF0000u);
}
__device__ __forceinline__ float bf_lo(unsigned u) {
    return __uint_as_float(u << 16);
}
__device__ __forceinline__ float bf_hi(unsigned u) {
    return __uint_as_float(u & 0xFFFF0000u);
}

// 32768 threads: gid<16384 -> x table, else z table ([j][b], coalesced reads).
// Also zeroes out[] (32768 elements).
__global__ void precompute_kernel(const float* __restrict__ x,
                                  const float* __restrict__ z,
                                  const float* __restrict__ borders,
                                  const float* __restrict__ inv_len,
                                  float2* __restrict__ xc,   // [32*512]
                                  uint2* __restrict__ zc,    // [32*512]
                                  float* __restrict__ out) {
    const int gid = blockIdx.x * blockDim.x + threadIdx.x;
    out[gid] = 0.f;
    int idx; float w;
    if (gid < IN_X * BATCH) {
        grid_coord(x[gid], borders, inv_len, idx, w);
        xc[gid] = make_float2(w, __int_as_float(idx * XSTR_A));
    } else {
        const int g = gid - IN_X * BATCH;   // g = j*512 + b (z's own layout)
        grid_coord(z[g], borders, inv_len, idx, w);
        zc[g] = make_uint2(__float_as_uint(w), (unsigned)(idx * CSTRIDE));
    }
}

__global__ __launch_bounds__(1024, 1)
void bf2d_kernel(const float2* __restrict__ xc,
                 const uint2* __restrict__ zc,
                 const float* __restrict__ P,
                 float* __restrict__ out) {
    // lds[cell*133 + il*33 + j] = packed bf16 (P[cell,o0,i,j], P[cell,o1,i,j])
    __shared__ unsigned lds[CELLS * CSTRIDE];   // 38437 dwords = 153748 B

    const int tid = threadIdx.x;                // 1024 threads
    const int op  = blockIdx.x & 31;            // o-pair
    const int iq  = blockIdx.x >> 5;            // i-quad 0..7
    const int o0  = op * 2;

    // ---- stage P[:, o0:o0+2, iq*4:(iq+1)*4, :] : 512-B stripes per (cell,o)
    // P float index: cell*65536 + o*1024 + i*32 + j
    const float* Pb = P + (size_t)o0 * 1024 + iq * 128;
    #pragma unroll
    for (int it = 0; it < 10; ++it) {
        const int k = tid + it * 1024;
        if (k < STASKS) {
            const int c  = k >> 5;
            const int f4 = k & 31;              // il = f4>>3, j4 = (f4&7)*4
            const float* g = Pb + (size_t)c * 65536 + f4 * 4;
            const float4 a = *(const float4*)g;           // o0 stripe
            const float4 b = *(const float4*)(g + 1024);  // o1 stripe
            unsigned* d = &lds[c * CSTRIDE + (f4 >> 3) * ILSTRIDE
                               + ((f4 & 7) << 2)];
            d[0] = pack_bf16(a.x, b.x);
            d[1] = pack_bf16(a.y, b.y);
            d[2] = pack_bf16(a.z, b.z);
            d[3] = pack_bf16(a.w, b.w);
        }
    }
    __syncthreads();

    // ---- per-thread: batch b, two local i's (il = 2*ih, 2*ih+1) ----
    const int b  = tid & (BATCH - 1);
    const int ih = tid >> 9;                    // 0 or 1
    const int il0 = 2 * ih, il1 = 2 * ih + 1;

    const float2 x0 = xc[(iq * 4 + il0) * BATCH + b];
    const float2 x1 = xc[(iq * 4 + il1) * BATCH + b];
    const float wx0 = x0.x, wx1 = x1.x;
    const int   xo0 = __float_as_int(x0.y) + il0 * ILSTRIDE;
    const int   xo1 = __float_as_int(x1.y) + il1 * ILSTRIDE;

    const uint2* zp = zc + b;
    float accx = 0.f, accy = 0.f;
    #pragma unroll 4
    for (int j = 0; j < IN_Z; ++j) {
        const uint2 zv = zp[j * BATCH];         // coalesced, L2-resident
        const float wz = __uint_as_float(zv.x);
        const int   zo = (int)zv.y + j;
        {
            const int base = xo0 + zo;
            const unsigned a0 = lds[base];
            const unsigned a1 = lds[base + CSTRIDE];          // ds_read2 pair
            const unsigned b0 = lds[base + XSTR_A];
            const unsigned b1 = lds[base + XSTR_A + CSTRIDE]; // ds_read2 pair
            const float lox = bf_lo(a0) + wz * (bf_lo(a1) - bf_lo(a0));
            const float loy = bf_hi(a0) + wz * (bf_hi(a1) - bf_hi(a0));
            const float hix = bf_lo(b0) + wz * (bf_lo(b1) - bf_lo(b0));
            const float hiy = bf_hi(b0) + wz * (bf_hi(b1) - bf_hi(b0));
            accx += lox + wx0 * (hix - lox);
            accy += loy + wx0 * (hiy - loy);
        }
        {
            const int base = xo1 + zo;
            const unsigned a0 = lds[base];
            const unsigned a1 = lds[base + CSTRIDE];
            const unsigned b0 = lds[base + XSTR_A];
            const unsigned b1 = lds[base + XSTR_A + CSTRIDE];
            const float lox = bf_lo(a0) + wz * (bf_lo(a1) - bf_lo(a0));
            const float loy = bf_hi(a0) + wz * (bf_hi(a1) - bf_hi(a0));
            const float hix = bf_lo(b0) + wz * (bf_lo(b1) - bf_lo(b0));
            const float hiy = bf_hi(b0) + wz * (bf_hi(b1) - bf_hi(b0));
            accx += lox + wx1 * (hix - lox);
            accy += loy + wx1 * (hiy - loy);
        }
    }

    atomicAdd(&out[o0 * BATCH + b],       accx);
    atomicAdd(&out[(o0 + 1) * BATCH + b], accy);
}

extern "C" void kernel_launch(void* const* d_in, const int* in_sizes, int n_in,
                              void* d_out, int out_size, void* d_ws, size_t ws_size,
                              hipStream_t stream) {
    const float* x       = (const float*)d_in[0];   // (32, 512)
    const float* z       = (const float*)d_in[1];   // (32, 512)
    const float* P       = (const float*)d_in[2];   // (17,17,64,32,32)
    const float* borders = (const float*)d_in[3];   // (17,)
    const float* inv_len = (const float*)d_in[4];   // (16,)
    float* out = (float*)d_out;                     // (64, 512) = 32768

    float2* xc = (float2*)d_ws;                     // 16384 float2
    uint2*  zc = (uint2*)(xc + IN_X * BATCH);       // 16384 uint2

    precompute_kernel<<<dim3(128), dim3(256), 0, stream>>>(
        x, z, borders, inv_len, xc, zc, out);

    bf2d_kernel<<<dim3(32 * 8), dim3(1024), 0, stream>>>(xc, zc, P, out);
}